// Round 5
// baseline (10339.910 us; speedup 1.0000x reference)
//
#include <hip/hip_runtime.h>

#define BB  64
#define TT  256
#define INF 512
#define HH  1024
#define CC  128

typedef __attribute__((ext_vector_type(8))) short bf16x8;
typedef __attribute__((ext_vector_type(4))) float f32x4;
typedef unsigned long long ull_t;
typedef unsigned short u16;

#define W0_LD 1544   // 1536+8
#define W1_LD 2056   // 2048+8
#define WC_LD 1032   // 1024+8
#define GSC_OFF (16*W0_LD + 16*W1_LD + 16*WC_LD)
#define SMEM_BYTES (GSC_OFF*2 + 2*(4*16*17)*4)   // 156928 B

#define HBUF (BB*HH)                  // elements per h generation
#define WS_HBYTES (8*HBUF*2)          // h0[4] + h1[4] rings, bf16 (1 MiB)
#define WS_ZERO_BYTES (WS_HBYTES + 4096)

__device__ __forceinline__ u16 f2bf(float f) {
    union { float f; unsigned u; } v; v.f = f;
    unsigned r = v.u + 0x7fffu + ((v.u >> 16) & 1u);   // RNE
    return (u16)(r >> 16);
}
__device__ __forceinline__ float sigm(float x) { return 1.f / (1.f + __expf(-x)); }

#define MFMA(a,b,c) __builtin_amdgcn_mfma_f32_16x16x32_bf16((a),(b),(c),0,0,0)

// wave-parallel scan of 256 monotonic slots; exits when all >= tgt
#define DETECT(basep, tgt) do { \
        const ull_t* sp_ = (const ull_t*)(basep) + (lane << 1); \
        const unsigned tg_ = (unsigned)(tgt); \
        for (;;) { \
            ull_t a_ = __hip_atomic_load(sp_,     __ATOMIC_RELAXED, __HIP_MEMORY_SCOPE_AGENT); \
            ull_t b_ = __hip_atomic_load(sp_ + 1, __ATOMIC_RELAXED, __HIP_MEMORY_SCOPE_AGENT); \
            bool ok_ = ((unsigned)a_ >= tg_) && ((unsigned)(a_ >> 32) >= tg_) && \
                       ((unsigned)b_ >= tg_) && ((unsigned)(b_ >> 32) >= tg_); \
            if (__all(ok_)) break; \
        } \
    } while (0)

#define ACQ() __builtin_amdgcn_fence(__ATOMIC_ACQUIRE, "agent")

__global__ __launch_bounds__(256, 1)
void lstm_persist(const float* __restrict__ xs,
                  const float* __restrict__ Wih0, const float* __restrict__ Whh0,
                  const float* __restrict__ bih0, const float* __restrict__ bhh0,
                  const float* __restrict__ Wih1, const float* __restrict__ Whh1,
                  const float* __restrict__ bih1, const float* __restrict__ bhh1,
                  const float* __restrict__ Wcls, const float* __restrict__ bcls,
                  float* __restrict__ out,          // f32 [B][C][2T]
                  u16* __restrict__ hws,            // h rings (bf16)
                  unsigned* __restrict__ bar)       // slots0[256] + slots1[256]
{
    extern __shared__ char smem[];
    u16* W0s = (u16*)smem;              // [16][W0_LD]  [W_hh0 | W_ih0]
    u16* W1s = W0s + 16*W0_LD;          // [16][W1_LD]  [W_ih1 | W_hh1]
    u16* WCs = W1s + 16*W1_LD;          // [16][WC_LD]  W_cls slice (blocks 0..63)
    float* gsc0 = (float*)(smem + GSC_OFF*2);       // [4][16][17]
    float* gsc1 = gsc0 + 4*16*17;

    const int blk   = blockIdx.x;       // owns h-cols 4*blk..4*blk+3 (both layers)
    const int tid   = threadIdx.x;
    const int wave  = tid >> 6;
    const int lane  = tid & 63;
    const int col16 = lane & 15;
    const int kgrp  = (lane >> 4) << 3;

    unsigned* slots0 = bar;
    unsigned* slots1 = bar + 256;

    // ---- prologue: weights -> LDS (bf16)
    for (int i = tid; i < 16*1536; i += 256) {
        int r = i / 1536, k = i - r*1536;
        int gr = 4*blk + (r & 3) + HH*(r >> 2);
        float v = (k < HH) ? Whh0[gr*HH + k] : Wih0[gr*INF + (k - HH)];
        W0s[r*W0_LD + k] = f2bf(v);
    }
    for (int i = tid; i < 16*2048; i += 256) {
        int r = i >> 11, k = i & 2047;
        int gr = 4*blk + (r & 3) + HH*(r >> 2);
        float v = (k < HH) ? Wih1[gr*HH + k] : Whh1[gr*HH + (k - HH)];
        W1s[r*W1_LD + k] = f2bf(v);
    }
    if (blk < 64) {
        int cb = (blk & 7) << 4;
        for (int i = tid; i < 16*1024; i += 256) {
            int r = i >> 10, k = i & 1023;
            WCs[r*WC_LD + k] = f2bf(Wcls[(cb + r)*HH + k]);
        }
    }
    const int   grl   = 4*blk + (col16 & 3) + HH*(col16 >> 2);
    const float bias0 = bih0[grl] + bhh0[grl];
    const float bias1 = bih1[grl] + bhh1[grl];
    const float biasc = (blk < 64) ? bcls[((blk & 7) << 4) + col16] : 0.f;

    float c0 = 0.f, c1 = 0.f;
    __syncthreads();

    const int  arow = (wave << 4) + col16;
    const u16* w0p  = W0s + col16*W0_LD + kgrp;
    const u16* w1p  = W1s + col16*W1_LD + kgrp;
    const u16* wcp  = WCs + col16*WC_LD + kgrp;

#define XPART(tx) do { \
        const float* xp = xs + (arow*TT + (tx))*INF + kgrp; \
        _Pragma("unroll 4") \
        for (int kc = 0; kc < 16; ++kc) { \
            const float4 x0 = *(const float4*)(xp + (kc << 5)); \
            const float4 x1 = *(const float4*)(xp + (kc << 5) + 4); \
            bf16x8 a; \
            a[0]=(short)f2bf(x0.x); a[1]=(short)f2bf(x0.y); a[2]=(short)f2bf(x0.z); a[3]=(short)f2bf(x0.w); \
            a[4]=(short)f2bf(x1.x); a[5]=(short)f2bf(x1.y); a[6]=(short)f2bf(x1.z); a[7]=(short)f2bf(x1.w); \
            const bf16x8 b = *(const bf16x8*)(w0p + ((32 + kc) << 5)); \
            if (kc & 1) g0B = MFMA(a, b, g0B); else g0A = MFMA(a, b, g0A); \
        } } while (0)

#define CLS(hbase, tcol) do { \
        f32x4 ca = { biasc, biasc, biasc, biasc }, cd = { 0.f, 0.f, 0.f, 0.f }; \
        const u16* hp = (hbase) + arow*HH + kgrp; \
        _Pragma("unroll 4") \
        for (int kc = 0; kc < 32; ++kc) { \
            const bf16x8 a = *(const bf16x8*)(hp + (kc << 5)); \
            const bf16x8 b = *(const bf16x8*)(wcp + (kc << 5)); \
            if (kc & 1) cd = MFMA(a, b, cd); else ca = MFMA(a, b, ca); \
        } \
        const int cc = ((blk & 7) << 4) + col16; \
        _Pragma("unroll") \
        for (int qq = 0; qq < 4; ++qq) { \
            const int br = (wave << 4) + ((lane >> 4) << 2) + qq; \
            __builtin_nontemporal_store(ca[qq] + cd[qq], &out[(br*CC + cc)*(2*TT) + (tcol)]); \
        } } while (0)

    f32x4 g0A = { bias0, bias0, bias0, bias0 }, g0B = { 0.f, 0.f, 0.f, 0.f };
    XPART(0);   // prime x-projection for t=0

    const int rloc = lane >> 2, jj = lane & 3;

    for (int t = 0; t <= TT; ++t) {
        const u16* h0rd = hws + (unsigned)((t + 3) & 3)*HBUF;            // h0(t-1)
        u16*       h0wr = hws + (unsigned)(t & 3)*HBUF;                  // h0(t)
        const u16* h1rd = hws + 4*HBUF + (unsigned)((t + 2) & 3)*HBUF;   // h1(t-2)
        u16*       h1wr = hws + 4*HBUF + (unsigned)((t + 3) & 3)*HBUF;   // h1(t-1)

        // ===== A: layer-0 step t — THE critical path =====
        if (t < TT) {
            if (t > 0) DETECT(slots0, t);            // h0(t-1) ready everywhere
            ACQ();
            const u16* h0p = h0rd + arow*HH + kgrp;
            #pragma unroll 4
            for (int kc = 0; kc < 32; ++kc) {
                const bf16x8 a = *(const bf16x8*)(h0p + (kc << 5));
                const bf16x8 b = *(const bf16x8*)(w0p + (kc << 5));
                if (kc & 1) g0B = MFMA(a, b, g0B);
                else        g0A = MFMA(a, b, g0A);
            }
            #pragma unroll
            for (int qq = 0; qq < 4; ++qq)
                gsc0[wave*272 + (((lane >> 4) << 2) + qq)*17 + col16] = g0A[qq] + g0B[qq];
            asm volatile("s_waitcnt lgkmcnt(0)" ::: "memory");
            const float* g = gsc0 + wave*272 + rloc*17;
            const float ig = sigm(g[jj]), fg = sigm(g[4 + jj]);
            const float gt = tanhf(g[8 + jj]), og = sigm(g[12 + jj]);
            c0 = fg*c0 + ig*gt;
            unsigned v = f2bf(og * tanhf(c0));
            unsigned p = v | (__shfl_down(v, 1) << 16);
            ull_t all = ((ull_t)__shfl_down(p, 2) << 32) | (ull_t)p;
            if (jj == 0)
                __hip_atomic_store((ull_t*)(h0wr + ((wave << 4) + rloc)*HH + (blk << 2)),
                                   all, __ATOMIC_RELAXED, __HIP_MEMORY_SCOPE_AGENT);
            asm volatile("s_waitcnt vmcnt(0)" ::: "memory");
            __syncthreads();
            if (tid == 0)
                __hip_atomic_store(&slots0[blk], (unsigned)(t + 1),
                                   __ATOMIC_RELAXED, __HIP_MEMORY_SCOPE_AGENT);
        }

        // ===== B: layer-1 step t-1 — slack work =====
        if (t >= 1) {
            if (t == TT) { DETECT(slots0, TT); }     // A skipped this step
            ACQ();
            f32x4 g1A = { bias1, bias1, bias1, bias1 }, g1B = { 0.f, 0.f, 0.f, 0.f };
            const u16* h0p = h0rd + arow*HH + kgrp;
            #pragma unroll 4
            for (int kc = 0; kc < 32; ++kc) {        // h0(t-1) part
                const bf16x8 a = *(const bf16x8*)(h0p + (kc << 5));
                const bf16x8 b = *(const bf16x8*)(w1p + (kc << 5));
                if (kc & 1) g1B = MFMA(a, b, g1B);
                else        g1A = MFMA(a, b, g1A);
            }
            DETECT(slots1, t - 1);                   // h1(t-2) ready (stale hit)
            ACQ();
            const u16* h1p = h1rd + arow*HH + kgrp;
            #pragma unroll 4
            for (int kc = 0; kc < 32; ++kc) {        // h1(t-2) part
                const bf16x8 a = *(const bf16x8*)(h1p + (kc << 5));
                const bf16x8 b = *(const bf16x8*)(w1p + ((32 + kc) << 5));
                if (kc & 1) g1B = MFMA(a, b, g1B);
                else        g1A = MFMA(a, b, g1A);
            }
            #pragma unroll
            for (int qq = 0; qq < 4; ++qq)
                gsc1[wave*272 + (((lane >> 4) << 2) + qq)*17 + col16] = g1A[qq] + g1B[qq];
            asm volatile("s_waitcnt lgkmcnt(0)" ::: "memory");
            const float* g = gsc1 + wave*272 + rloc*17;
            const float ig = sigm(g[jj]), fg = sigm(g[4 + jj]);
            const float gt = tanhf(g[8 + jj]), og = sigm(g[12 + jj]);
            c1 = fg*c1 + ig*gt;
            unsigned v = f2bf(og * tanhf(c1));
            unsigned p = v | (__shfl_down(v, 1) << 16);
            ull_t all = ((ull_t)__shfl_down(p, 2) << 32) | (ull_t)p;
            if (jj == 0)
                __hip_atomic_store((ull_t*)(h1wr + ((wave << 4) + rloc)*HH + (blk << 2)),
                                   all, __ATOMIC_RELAXED, __HIP_MEMORY_SCOPE_AGENT);
            asm volatile("s_waitcnt vmcnt(0)" ::: "memory");
            __syncthreads();
            if (tid == 0)
                __hip_atomic_store(&slots1[blk], (unsigned)t,
                                   __ATOMIC_RELAXED, __HIP_MEMORY_SCOPE_AGENT);
        }

        // ===== C: hide under next step's detect window =====
        if (t + 1 < TT) {                            // x-projection for t+1
            g0A[0] = bias0; g0A[1] = bias0; g0A[2] = bias0; g0A[3] = bias0;
            g0B[0] = 0.f;   g0B[1] = 0.f;   g0B[2] = 0.f;   g0B[3] = 0.f;
            XPART(t + 1);
        }
        if (blk < 32 && wave == (blk >> 3) && t >= 1)                     // l0(t-1)
            CLS(h0rd, ((t - 1) << 1));
        if (blk >= 32 && blk < 64 && wave == ((blk - 32) >> 3) && t >= 2) // l1(t-2)
            CLS(h1rd, (((t - 2) << 1) + 1));
    }

    // ---- post-loop: l1(TT-1)
    if (blk >= 32 && blk < 64 && wave == ((blk - 32) >> 3)) {
        DETECT(slots1, TT);
        ACQ();
        CLS(hws + 4*HBUF + (unsigned)((TT + 3) & 3)*HBUF, (((TT - 1) << 1) + 1));
    }
}

extern "C" void kernel_launch(void* const* d_in, const int* in_sizes, int n_in,
                              void* d_out, int out_size, void* d_ws, size_t ws_size,
                              hipStream_t stream) {
    const float* xs   = (const float*)d_in[0];
    const float* Wih0 = (const float*)d_in[1];
    const float* Whh0 = (const float*)d_in[2];
    const float* bih0 = (const float*)d_in[3];
    const float* bhh0 = (const float*)d_in[4];
    const float* Wih1 = (const float*)d_in[5];
    const float* Whh1 = (const float*)d_in[6];
    const float* bih1 = (const float*)d_in[7];
    const float* bhh1 = (const float*)d_in[8];
    const float* Wcls = (const float*)d_in[9];
    const float* bcls = (const float*)d_in[10];
    float* out = (float*)d_out;
    u16*      hws = (u16*)d_ws;
    unsigned* bar = (unsigned*)((char*)d_ws + WS_HBYTES);

    (void)hipMemsetAsync(d_ws, 0, WS_ZERO_BYTES, stream);

    (void)hipFuncSetAttribute((const void*)lstm_persist,
                              hipFuncAttributeMaxDynamicSharedMemorySize, SMEM_BYTES);

    lstm_persist<<<dim3(256), dim3(256), SMEM_BYTES, stream>>>(
        xs, Wih0, Whh0, bih0, bhh0, Wih1, Whh1, bih1, bhh1, Wcls, bcls,
        out, hws, bar);
}

// Round 6
// 7637.568 us; speedup vs baseline: 1.3538x; 1.3538x over previous
//
#include <hip/hip_runtime.h>

#define BB  64
#define TT  256
#define INF 512
#define HH  1024
#define CC  128

typedef __attribute__((ext_vector_type(8))) short bf16x8;
typedef __attribute__((ext_vector_type(4))) float f32x4;
typedef unsigned long long ull_t;
typedef unsigned short u16;

#define W0_LD 1544   // 1536+8
#define W1_LD 2056   // 2048+8
#define WC_LD 1032   // 1024+8
#define GSC_OFF (16*W0_LD + 16*W1_LD + 16*WC_LD)
#define SMEM_BYTES (GSC_OFF*2 + 2*(4*16*17)*4)   // 156928 B

#define HBUF (BB*HH)                  // elements per h generation
#define WS_HBYTES (8*HBUF*2)          // h0[4] + h1[4] rings, bf16 (1 MiB)
#define WS_ZERO_BYTES (WS_HBYTES + 16384)

#define AGENT __HIP_MEMORY_SCOPE_AGENT
#define RLX   __ATOMIC_RELAXED
#define ACQ() __builtin_amdgcn_fence(__ATOMIC_ACQUIRE, "agent")

__device__ __forceinline__ u16 f2bf(float f) {
    union { float f; unsigned u; } v; v.f = f;
    unsigned r = v.u + 0x7fffu + ((v.u >> 16) & 1u);   // RNE
    return (u16)(r >> 16);
}
__device__ __forceinline__ float sigm(float x) { return 1.f / (1.f + __expf(-x)); }

#define MFMA(a,b,c) __builtin_amdgcn_mfma_f32_16x16x32_bf16((a),(b),(c),0,0,0)

__global__ __launch_bounds__(320, 1)
void lstm_persist(const float* __restrict__ xs,
                  const float* __restrict__ Wih0, const float* __restrict__ Whh0,
                  const float* __restrict__ bih0, const float* __restrict__ bhh0,
                  const float* __restrict__ Wih1, const float* __restrict__ Whh1,
                  const float* __restrict__ bih1, const float* __restrict__ bhh1,
                  const float* __restrict__ Wcls, const float* __restrict__ bcls,
                  float* __restrict__ out,          // f32 [B][C][2T]
                  u16* __restrict__ hws,            // h rings (bf16)
                  unsigned* __restrict__ bar)       // slots0[1024] slots1[1024] flags[8 lines]
{
    extern __shared__ char smem[];
    u16* W0s = (u16*)smem;              // [16][W0_LD]  [W_hh0 | W_ih0]
    u16* W1s = W0s + 16*W0_LD;          // [16][W1_LD]  [W_ih1 | W_hh1]
    u16* WCs = W1s + 16*W1_LD;          // [16][WC_LD]  W_cls slice (blocks 0..63)
    float* gsc0 = (float*)(smem + GSC_OFF*2);       // [4][16][17]
    float* gsc1 = gsc0 + 4*16*17;

    const int blk   = blockIdx.x;       // owns h-cols 4*blk..4*blk+3 (both layers)
    const int tid   = threadIdx.x;
    const int wave  = tid >> 6;         // 0..3 workers, 4 = manager/exit
    const int lane  = tid & 63;
    const int col16 = lane & 15;
    const int kgrp  = (lane >> 4) << 3;

    // ---- prologue: weights -> LDS (bf16), all 5 waves help
    for (int i = tid; i < 16*1536; i += 320) {
        int r = i / 1536, k = i - r*1536;
        int gr = 4*blk + (r & 3) + HH*(r >> 2);
        float v = (k < HH) ? Whh0[gr*HH + k] : Wih0[gr*INF + (k - HH)];
        W0s[r*W0_LD + k] = f2bf(v);
    }
    for (int i = tid; i < 16*2048; i += 320) {
        int r = i >> 11, k = i & 2047;
        int gr = 4*blk + (r & 3) + HH*(r >> 2);
        float v = (k < HH) ? Wih1[gr*HH + k] : Whh1[gr*HH + (k - HH)];
        W1s[r*W1_LD + k] = f2bf(v);
    }
    if (blk < 64) {
        int cb = (blk & 7) << 4;
        for (int i = tid; i < 16*1024; i += 320) {
            int r = i >> 10, k = i & 1023;
            WCs[r*WC_LD + k] = f2bf(Wcls[(cb + r)*HH + k]);
        }
    }
    __syncthreads();   // LDS weights ready (only barrier in the kernel)

    // ---- manager wave: block 255 wave 4 scans slots, publishes replicated flags
    if (wave == 4) {
        if (blk == 255) {
            const ull_t* s0 = (const ull_t*)bar;            // 512 ull
            const ull_t* s1 = (const ull_t*)(bar + 1024);   // 512 ull
            ull_t* flags = (ull_t*)(bar + 2048);
            unsigned v0 = 0, v1 = 0;
            while (v1 < TT) {
                bool ok0 = true, ok1 = true;
                #pragma unroll
                for (int j = 0; j < 8; ++j) {
                    ull_t a = __hip_atomic_load(s0 + lane*8 + j, RLX, AGENT);
                    ok0 &= ((unsigned)a >= v0 + 1) && ((unsigned)(a >> 32) >= v0 + 1);
                }
                #pragma unroll
                for (int j = 0; j < 8; ++j) {
                    ull_t a = __hip_atomic_load(s1 + lane*8 + j, RLX, AGENT);
                    ok1 &= ((unsigned)a >= v1 + 1) && ((unsigned)(a >> 32) >= v1 + 1);
                }
                bool adv = false;
                if (__all(ok0) && v0 < TT) { ++v0; adv = true; }
                if (__all(ok1) && v1 < TT) { ++v1; adv = true; }
                if (adv && lane == 0) {
                    ull_t pk = (ull_t)v0 | ((ull_t)v1 << 32);
                    #pragma unroll
                    for (int g = 0; g < 8; ++g)
                        __hip_atomic_store(flags + g*16, pk, RLX, AGENT);
                }
            }
        }
        return;
    }

    const int   grl   = 4*blk + (col16 & 3) + HH*(col16 >> 2);
    const float bias0 = bih0[grl] + bhh0[grl];
    const float bias1 = bih1[grl] + bhh1[grl];
    const float biasc = (blk < 64) ? bcls[((blk & 7) << 4) + col16] : 0.f;

    float c0 = 0.f, c1 = 0.f;

    const int  gid  = (blk << 2) + wave;           // per-wave slot id
    const int  arow = (wave << 4) + col16;
    const u16* w0p  = W0s + col16*W0_LD + kgrp;
    const u16* w1p  = W1s + col16*W1_LD + kgrp;
    const u16* wcp  = WCs + col16*WC_LD + kgrp;
    unsigned* slots0 = bar;
    unsigned* slots1 = bar + 1024;
    const ull_t* myflag = (const ull_t*)(bar + 2048) + (blk & 7)*16;

#define XPART(tx) do { \
        const float* xp = xs + (arow*TT + (tx))*INF + kgrp; \
        _Pragma("unroll 4") \
        for (int kc = 0; kc < 16; ++kc) { \
            const float4 x0 = *(const float4*)(xp + (kc << 5)); \
            const float4 x1 = *(const float4*)(xp + (kc << 5) + 4); \
            bf16x8 a; \
            a[0]=(short)f2bf(x0.x); a[1]=(short)f2bf(x0.y); a[2]=(short)f2bf(x0.z); a[3]=(short)f2bf(x0.w); \
            a[4]=(short)f2bf(x1.x); a[5]=(short)f2bf(x1.y); a[6]=(short)f2bf(x1.z); a[7]=(short)f2bf(x1.w); \
            const bf16x8 b = *(const bf16x8*)(w0p + ((32 + kc) << 5)); \
            if (kc & 1) g0B = MFMA(a, b, g0B); else g0A = MFMA(a, b, g0A); \
        } } while (0)

#define CLS(hbase, tcol) do { \
        f32x4 ca = { biasc, biasc, biasc, biasc }, cd = { 0.f, 0.f, 0.f, 0.f }; \
        const u16* hp = (hbase) + arow*HH + kgrp; \
        _Pragma("unroll 4") \
        for (int kc = 0; kc < 32; ++kc) { \
            const bf16x8 a = *(const bf16x8*)(hp + (kc << 5)); \
            const bf16x8 b = *(const bf16x8*)(wcp + (kc << 5)); \
            if (kc & 1) cd = MFMA(a, b, cd); else ca = MFMA(a, b, ca); \
        } \
        const int cc = ((blk & 7) << 4) + col16; \
        _Pragma("unroll") \
        for (int qq = 0; qq < 4; ++qq) { \
            const int br = (wave << 4) + ((lane >> 4) << 2) + qq; \
            __builtin_nontemporal_store(ca[qq] + cd[qq], &out[(br*CC + cc)*(2*TT) + (tcol)]); \
        } } while (0)

    f32x4 g0A = { bias0, bias0, bias0, bias0 }, g0B = { 0.f, 0.f, 0.f, 0.f };
    XPART(0);   // prime x-projection for t=0

    const int rloc = lane >> 2, jj = lane & 3;

    for (int t = 0; t <= TT; ++t) {
        const u16* h0rd = hws + (unsigned)((t + 3) & 3)*HBUF;            // h0(t-1)
        u16*       h0wr = hws + (unsigned)(t & 3)*HBUF;                  // h0(t)
        const u16* h1rd = hws + 4*HBUF + (unsigned)((t + 2) & 3)*HBUF;   // h1(t-2)
        u16*       h1wr = hws + 4*HBUF + (unsigned)((t + 3) & 3)*HBUF;   // h1(t-1)

        // ---- wait: h0(t-1) and h1(t-2) visible
        if (t > 0) {
            const unsigned need0 = (unsigned)t, need1 = (unsigned)(t - 1);
            for (;;) {
                ull_t F = __hip_atomic_load(myflag, RLX, AGENT);
                if ((unsigned)F >= need0 && (unsigned)(F >> 32) >= need1) break;
                __builtin_amdgcn_s_sleep(1);
            }
            ACQ();
        }

        f32x4 g1A = { bias1, bias1, bias1, bias1 }, g1B = { 0.f, 0.f, 0.f, 0.f };
        const u16* h0p = h0rd + arow*HH + kgrp;

        if (t < TT) {
            // fused: g0 h-part + g1 h0-part share A fragments
            #pragma unroll 4
            for (int kc = 0; kc < 32; ++kc) {
                const bf16x8 a  = *(const bf16x8*)(h0p + (kc << 5));
                const bf16x8 b0 = *(const bf16x8*)(w0p + (kc << 5));
                const bf16x8 b1 = *(const bf16x8*)(w1p + (kc << 5));
                if (kc & 1) { g0B = MFMA(a, b0, g0B); g1B = MFMA(a, b1, g1B); }
                else        { g0A = MFMA(a, b0, g0A); g1A = MFMA(a, b1, g1A); }
            }
            // cell0 + earliest possible h0 release
            #pragma unroll
            for (int qq = 0; qq < 4; ++qq)
                gsc0[wave*272 + (((lane >> 4) << 2) + qq)*17 + col16] = g0A[qq] + g0B[qq];
            asm volatile("s_waitcnt lgkmcnt(0)" ::: "memory");
            const float* g = gsc0 + wave*272 + rloc*17;
            const float ig = sigm(g[jj]), fg = sigm(g[4 + jj]);
            const float gt = tanhf(g[8 + jj]), og = sigm(g[12 + jj]);
            c0 = fg*c0 + ig*gt;
            unsigned v = f2bf(og * tanhf(c0));
            unsigned p = v | (__shfl_down(v, 1) << 16);
            ull_t all = ((ull_t)__shfl_down(p, 2) << 32) | (ull_t)p;
            if (jj == 0)
                __hip_atomic_store((ull_t*)(h0wr + ((wave << 4) + rloc)*HH + (blk << 2)),
                                   all, RLX, AGENT);
            asm volatile("s_waitcnt vmcnt(0)" ::: "memory");
            if (lane == 0)
                __hip_atomic_store(&slots0[gid], (unsigned)(t + 1), RLX, AGENT);
        } else {
            // t == TT: only g1's h0-part
            #pragma unroll 4
            for (int kc = 0; kc < 32; ++kc) {
                const bf16x8 a  = *(const bf16x8*)(h0p + (kc << 5));
                const bf16x8 b1 = *(const bf16x8*)(w1p + (kc << 5));
                if (kc & 1) g1B = MFMA(a, b1, g1B);
                else        g1A = MFMA(a, b1, g1A);
            }
        }

        if (t >= 1) {
            // g1 h1-part, cell1, release h1(t-1)
            const u16* h1p = h1rd + arow*HH + kgrp;
            #pragma unroll 4
            for (int kc = 0; kc < 32; ++kc) {
                const bf16x8 a = *(const bf16x8*)(h1p + (kc << 5));
                const bf16x8 b = *(const bf16x8*)(w1p + ((32 + kc) << 5));
                if (kc & 1) g1B = MFMA(a, b, g1B);
                else        g1A = MFMA(a, b, g1A);
            }
            #pragma unroll
            for (int qq = 0; qq < 4; ++qq)
                gsc1[wave*272 + (((lane >> 4) << 2) + qq)*17 + col16] = g1A[qq] + g1B[qq];
            asm volatile("s_waitcnt lgkmcnt(0)" ::: "memory");
            const float* g = gsc1 + wave*272 + rloc*17;
            const float ig = sigm(g[jj]), fg = sigm(g[4 + jj]);
            const float gt = tanhf(g[8 + jj]), og = sigm(g[12 + jj]);
            c1 = fg*c1 + ig*gt;
            unsigned v = f2bf(og * tanhf(c1));
            unsigned p = v | (__shfl_down(v, 1) << 16);
            ull_t all = ((ull_t)__shfl_down(p, 2) << 32) | (ull_t)p;
            if (jj == 0)
                __hip_atomic_store((ull_t*)(h1wr + ((wave << 4) + rloc)*HH + (blk << 2)),
                                   all, RLX, AGENT);
            asm volatile("s_waitcnt vmcnt(0)" ::: "memory");
            if (lane == 0)
                __hip_atomic_store(&slots1[gid], (unsigned)t, RLX, AGENT);
        }

        // ---- slack work (overlaps next poll window)
        if (t + 1 < TT) {
            g0A[0] = bias0; g0A[1] = bias0; g0A[2] = bias0; g0A[3] = bias0;
            g0B[0] = 0.f;   g0B[1] = 0.f;   g0B[2] = 0.f;   g0B[3] = 0.f;
            XPART(t + 1);
        }
        if (blk < 32 && wave == (blk >> 3) && t >= 1)                     // l0(t-1)
            CLS(h0rd, ((t - 1) << 1));
        if (blk >= 32 && blk < 64 && wave == ((blk - 32) >> 3) && t >= 2) // l1(t-2)
            CLS(h1rd, (((t - 2) << 1) + 1));
    }

    // ---- post-loop: l1(TT-1), needs h1(TT-1) => f1 >= TT
    if (blk >= 32 && blk < 64 && wave == ((blk - 32) >> 3)) {
        for (;;) {
            ull_t F = __hip_atomic_load(myflag, RLX, AGENT);
            if ((unsigned)(F >> 32) >= (unsigned)TT) break;
            __builtin_amdgcn_s_sleep(1);
        }
        ACQ();
        CLS(hws + 4*HBUF + (unsigned)((TT + 3) & 3)*HBUF, (((TT - 1) << 1) + 1));
    }
}

extern "C" void kernel_launch(void* const* d_in, const int* in_sizes, int n_in,
                              void* d_out, int out_size, void* d_ws, size_t ws_size,
                              hipStream_t stream) {
    const float* xs   = (const float*)d_in[0];
    const float* Wih0 = (const float*)d_in[1];
    const float* Whh0 = (const float*)d_in[2];
    const float* bih0 = (const float*)d_in[3];
    const float* bhh0 = (const float*)d_in[4];
    const float* Wih1 = (const float*)d_in[5];
    const float* Whh1 = (const float*)d_in[6];
    const float* bih1 = (const float*)d_in[7];
    const float* bhh1 = (const float*)d_in[8];
    const float* Wcls = (const float*)d_in[9];
    const float* bcls = (const float*)d_in[10];
    float* out = (float*)d_out;
    u16*      hws = (u16*)d_ws;
    unsigned* bar = (unsigned*)((char*)d_ws + WS_HBYTES);

    (void)hipMemsetAsync(d_ws, 0, WS_ZERO_BYTES, stream);

    (void)hipFuncSetAttribute((const void*)lstm_persist,
                              hipFuncAttributeMaxDynamicSharedMemorySize, SMEM_BYTES);

    lstm_persist<<<dim3(256), dim3(320), SMEM_BYTES, stream>>>(
        xs, Wih0, Whh0, bih0, bhh0, Wih1, Whh1, bih1, bhh1, Wcls, bcls,
        out, hws, bar);
}